// Round 18
// baseline (232.475 us; speedup 1.0000x reference)
//
#include <hip/hip_runtime.h>

// NCC2D fused: 5 box-sums (9x9, zero-pad) + cc + global mean.
// R10: REGISTER-RING + DEEP PREFETCH. R9 (stage-then-compute) measured WORSE
// (85us, VALU 19.5%, occ 13.5%): halved residency + serialized staging. The
// R6-R9 matrix isolates two per-step stalls in the best (R7/R8, ~50us) shape:
//   (1) 1-deep row prefetch x ~900cy HBM latency (FETCH=67MB every dispatch
//       -> inputs are NOT L3-resident across dispatches); 24x900 ~= the
//       whole per-block time.
//   (2) LDS-ring ds_read + lgkmcnt wait (~120cy) on the V-update path.
// Fix, keeping everything proven good:
//   * R7 shape: 256 thr cover all 512 cols (2/thread) -> NO column halo.
//   * Ring of RAW rows in 36 NAMED float2 scalars (R5 proved straight-line
//     named scalars promote; raw rows are 2.5x smaller than R1's H-ring).
//   * Prefetch distance 4 (4 slots in flight) hides HBM latency under work.
//   * LDS = Vbuf exchange only (10.4KB) -> 1024 blocks = 4 blk/CU x 4 waves
//     = 16 waves/CU, all resident in one generation.
// d_ws: 1024 block partials (float). Kernel 2 reduces in double -> -mean.

#define BATCH   32
#define IMH     512
#define IMW     512
#define SH      16           // output rows per block
#define NSTRIP  32           // 512/16
#define NPART   (BATCH * NSTRIP)   // 1024
#define NK      24           // input rows per block (SH+8)
#define VROW    520          // 4 pad + 512 + 4 pad

// prefetch input row K (r0-4+K) into named float2 slots (OOB -> zeros)
#define PREF(K, PI, PJ) do {                                               \
    const int ri_ = r0 - 4 + (K);                                          \
    PI = make_float2(0.f, 0.f); PJ = make_float2(0.f, 0.f);                \
    if ((unsigned)ri_ < (unsigned)IMH) {                                   \
        PI = *(const float2*)(Ib + (size_t)ri_ * IMW + c0);                \
        PJ = *(const float2*)(Jb + (size_t)ri_ * IMW + c0);                \
    }                                                                      \
} while (0)

// horizontal 9-window sums for the thread's 2 cols from Vbuf row QI
#define HWIN(QI, HA, HB) do {                                              \
    const float2 w0_ = *(const float2*)&Vbuf[QI][c0];                      \
    const float2 w1_ = *(const float2*)&Vbuf[QI][c0 + 2];                  \
    const float2 w2_ = *(const float2*)&Vbuf[QI][c0 + 4];                  \
    const float2 w3_ = *(const float2*)&Vbuf[QI][c0 + 6];                  \
    const float2 w4_ = *(const float2*)&Vbuf[QI][c0 + 8];                  \
    HA = ((w0_.x + w0_.y) + (w1_.x + w1_.y))                               \
       + ((w2_.x + w2_.y) + (w3_.x + w3_.y)) + w4_.x;                      \
    HB = HA + w4_.y - w0_.x;                                               \
} while (0)

#define CC1(AI, AJ, S2, S3, S4) do {                                       \
    const float cross = (S4) - (AI)*(AJ)*inv81;                            \
    const float ivv   = (S2) - (AI)*(AI)*inv81;                            \
    const float jvv   = (S3) - (AJ)*(AJ)*inv81;                            \
    acc += cross * cross * __builtin_amdgcn_rcpf(ivv * jvv + 1e-5f);       \
} while (0)

// exchange V through LDS, horizontal 9-sums, accumulate cc for 2 cols
#define EMIT() do {                                                        \
    *(float2*)&Vbuf[0][4 + c0] = make_float2(VI0, VI1);                    \
    *(float2*)&Vbuf[1][4 + c0] = make_float2(VJ0, VJ1);                    \
    *(float2*)&Vbuf[2][4 + c0] = make_float2(VA0, VA1);                    \
    *(float2*)&Vbuf[3][4 + c0] = make_float2(VB0, VB1);                    \
    *(float2*)&Vbuf[4][4 + c0] = make_float2(VC0, VC1);                    \
    __syncthreads();                                                       \
    float HI0, HI1, HJ0, HJ1, HA0, HA1, HB0, HB1, HC0, HC1;                \
    HWIN(0, HI0, HI1);                                                     \
    HWIN(1, HJ0, HJ1);                                                     \
    HWIN(2, HA0, HA1);                                                     \
    HWIN(3, HB0, HB1);                                                     \
    HWIN(4, HC0, HC1);                                                     \
    CC1(HI0, HJ0, HA0, HB0, HC0);                                          \
    CC1(HI1, HJ1, HA1, HB1, HC1);                                          \
    __syncthreads();   /* WAR: next emit's writes vs these reads */        \
} while (0)

// one row step: consume prefetch slot (PI,PJ), update V (+new, -ring-old),
// rotate ring slot, emit when K>=8. K is a literal -> guards fold away.
#define STEP(K, PI, PJ, RI_, RJ_) do {                                     \
    if ((K) >= 9) {                                                        \
        VI0 -= RI_.x;        VI1 -= RI_.y;                                 \
        VJ0 -= RJ_.x;        VJ1 -= RJ_.y;                                 \
        VA0 -= RI_.x*RI_.x;  VA1 -= RI_.y*RI_.y;                           \
        VB0 -= RJ_.x*RJ_.x;  VB1 -= RJ_.y*RJ_.y;                           \
        VC0 -= RI_.x*RJ_.x;  VC1 -= RI_.y*RJ_.y;                           \
    }                                                                      \
    VI0 += PI.x;        VI1 += PI.y;                                       \
    VJ0 += PJ.x;        VJ1 += PJ.y;                                       \
    VA0 += PI.x*PI.x;   VA1 += PI.y*PI.y;                                  \
    VB0 += PJ.x*PJ.x;   VB1 += PJ.y*PJ.y;                                  \
    VC0 += PI.x*PJ.x;   VC1 += PI.y*PJ.y;                                  \
    RI_ = PI; RJ_ = PJ;                                                    \
    if ((K) >= 8) { EMIT(); }                                              \
} while (0)

__global__ __launch_bounds__(256, 4) void ncc_main(const float* __restrict__ I,
                                                   const float* __restrict__ J,
                                                   float* __restrict__ partial) {
    const int t  = threadIdx.x;          // 0..255
    const int s  = blockIdx.x;           // row strip (0..31)
    const int b  = blockIdx.y;           // image
    const int r0 = s * SH;
    const int c0 = 2 * t;                // first owned column (0..510)
    const float inv81 = 1.0f / 81.0f;

    const float* Ib = I + (size_t)b * IMH * IMW;
    const float* Jb = J + (size_t)b * IMH * IMW;

    __shared__ float Vbuf[5][VROW];      // 10.4 KB exchange buffer
    // zero the 8 pad cols (idx 0..3, 516..519) of each of the 5 rows
    if (t < 40) {
        const int q = t >> 3, p = t & 7;
        Vbuf[q][p < 4 ? p : 512 + p] = 0.f;
    }
    __syncthreads();

    const float2 z_ = make_float2(0.f, 0.f);
    // 9 ring slots of RAW rows (I pair, J pair), all named scalars
    float2 rIA = z_, rIB = z_, rIC = z_, rID = z_, rIE = z_,
           rIF = z_, rIG = z_, rIH = z_, rII = z_;
    float2 rJA = z_, rJB = z_, rJC = z_, rJD = z_, rJE = z_,
           rJF = z_, rJG = z_, rJH = z_, rJI = z_;
    // vertical 9-row running sums: I, J, II, JJ, IJ x 2 cols
    float VI0 = 0.f, VI1 = 0.f, VJ0 = 0.f, VJ1 = 0.f;
    float VA0 = 0.f, VA1 = 0.f, VB0 = 0.f, VB1 = 0.f;
    float VC0 = 0.f, VC1 = 0.f;
    float acc = 0.f;
    // 4 prefetch slots
    float2 pi0, pj0, pi1, pj1, pi2, pj2, pi3, pj3;

    PREF(0, pi0, pj0);
    PREF(1, pi1, pj1);
    PREF(2, pi2, pj2);
    PREF(3, pi3, pj3);

    STEP( 0, pi0, pj0, rIA, rJA);  PREF( 4, pi0, pj0);
    STEP( 1, pi1, pj1, rIB, rJB);  PREF( 5, pi1, pj1);
    STEP( 2, pi2, pj2, rIC, rJC);  PREF( 6, pi2, pj2);
    STEP( 3, pi3, pj3, rID, rJD);  PREF( 7, pi3, pj3);
    STEP( 4, pi0, pj0, rIE, rJE);  PREF( 8, pi0, pj0);
    STEP( 5, pi1, pj1, rIF, rJF);  PREF( 9, pi1, pj1);
    STEP( 6, pi2, pj2, rIG, rJG);  PREF(10, pi2, pj2);
    STEP( 7, pi3, pj3, rIH, rJH);  PREF(11, pi3, pj3);
    STEP( 8, pi0, pj0, rII, rJI);  PREF(12, pi0, pj0);
    STEP( 9, pi1, pj1, rIA, rJA);  PREF(13, pi1, pj1);
    STEP(10, pi2, pj2, rIB, rJB);  PREF(14, pi2, pj2);
    STEP(11, pi3, pj3, rIC, rJC);  PREF(15, pi3, pj3);
    STEP(12, pi0, pj0, rID, rJD);  PREF(16, pi0, pj0);
    STEP(13, pi1, pj1, rIE, rJE);  PREF(17, pi1, pj1);
    STEP(14, pi2, pj2, rIF, rJF);  PREF(18, pi2, pj2);
    STEP(15, pi3, pj3, rIG, rJG);  PREF(19, pi3, pj3);
    STEP(16, pi0, pj0, rIH, rJH);  PREF(20, pi0, pj0);
    STEP(17, pi1, pj1, rII, rJI);  PREF(21, pi1, pj1);
    STEP(18, pi2, pj2, rIA, rJA);  PREF(22, pi2, pj2);
    STEP(19, pi3, pj3, rIB, rJB);  PREF(23, pi3, pj3);
    STEP(20, pi0, pj0, rIC, rJC);
    STEP(21, pi1, pj1, rID, rJD);
    STEP(22, pi2, pj2, rIE, rJE);
    STEP(23, pi3, pj3, rIF, rJF);

    // block reduction: wave shuffle, then LDS across the 4 waves
    float sum = acc;
#pragma unroll
    for (int off = 32; off > 0; off >>= 1) sum += __shfl_down(sum, off, 64);

    __shared__ float wsum[4];
    if ((t & 63) == 0) wsum[t >> 6] = sum;
    __syncthreads();
    if (t == 0) {
        partial[(size_t)b * NSTRIP + s] = wsum[0] + wsum[1] + wsum[2] + wsum[3];
    }
}

__global__ __launch_bounds__(256) void ncc_reduce(const float* __restrict__ partial,
                                                  float* __restrict__ out) {
    const int t = threadIdx.x;
    double ssum = 0.0;
    for (int idx = t; idx < NPART; idx += 256) ssum += (double)partial[idx];
#pragma unroll
    for (int off = 32; off > 0; off >>= 1) ssum += __shfl_down(ssum, off, 64);

    __shared__ double wsum[4];
    if ((t & 63) == 0) wsum[t >> 6] = ssum;
    __syncthreads();
    if (t == 0) {
        const double total = wsum[0] + wsum[1] + wsum[2] + wsum[3];
        out[0] = (float)(-total / 8388608.0);  // -mean over 32*512*512
    }
}

extern "C" void kernel_launch(void* const* d_in, const int* in_sizes, int n_in,
                              void* d_out, int out_size, void* d_ws, size_t ws_size,
                              hipStream_t stream) {
    const float* I = (const float*)d_in[0];  // y_true
    const float* J = (const float*)d_in[1];  // y_pred
    float* partial = (float*)d_ws;           // NPART floats
    float* out     = (float*)d_out;

    dim3 grid(NSTRIP, BATCH);
    ncc_main<<<grid, 256, 0, stream>>>(I, J, partial);
    ncc_reduce<<<1, 256, 0, stream>>>(partial, out);
}

// Round 19
// 117.316 us; speedup vs baseline: 1.9816x; 1.9816x over previous
//
#include <hip/hip_runtime.h>

// NCC2D fused: 5 box-sums (9x9, zero-pad) + cc + global mean.
// R11 = R7 (session best: main ~48us, total 118.4us) + ONE change:
// register prefetch depth 1 -> 4. R10's register-ring attempt proved the
// allocator grants only ~52-88 VGPRs to barrier-containing loops (VGPR=64,
// 240MB spill, 6% VALU) -- so the 9-row history STAYS in the LDS ring
// (R7's structure) and only the prefetch pipeline lives in registers:
// 4 named float2 pairs (16 floats) consumed/reissued round-robin in a
// 6x4-unrolled K-loop. Issue-to-consume gap = 3 steps (~1200cy incl. emit
// barriers) >= ~900cy HBM latency that R7's 1-deep prefetch left exposed
// (R7/R8: VALU 24-28%, occ ~20%, per-step stall ~10x issue work).
// Live state ~45 floats -> fits the observed allocator budget, no spill.
// d_ws: 1024 block partials (float). Kernel 2 reduces in double -> -mean.

#define BATCH   32
#define IMH     512
#define IMW     512
#define SH      16           // output rows per block
#define NSTRIP  32           // 512/16
#define NPART   (BATCH * NSTRIP)   // 1024
#define NK      24           // input rows per block (SH+8); 24 = 6*4
#define VROW    520          // 4 pad + 512 + 4 pad

// guarded prefetch of input row KK (r0-4+KK) into named float2 pair
#define PREFG(KK, PI, PJ) do {                                             \
    const int kk_ = (KK);                                                  \
    const int ri_ = r0 - 4 + kk_;                                          \
    PI = make_float2(0.f, 0.f); PJ = make_float2(0.f, 0.f);                \
    if (kk_ < NK && (unsigned)ri_ < (unsigned)IMH) {                       \
        PI = *(const float2*)(Ib + (size_t)ri_ * IMW + c0);                \
        PJ = *(const float2*)(Jb + (size_t)ri_ * IMW + c0);                \
    }                                                                      \
} while (0)

// horizontal 9-window sums for the thread's 2 cols from Vbuf row QI
#define HWIN(QI, HA, HB) do {                                              \
    const float2 w0_ = *(const float2*)&Vbuf[QI][c0];                      \
    const float2 w1_ = *(const float2*)&Vbuf[QI][c0 + 2];                  \
    const float2 w2_ = *(const float2*)&Vbuf[QI][c0 + 4];                  \
    const float2 w3_ = *(const float2*)&Vbuf[QI][c0 + 6];                  \
    const float2 w4_ = *(const float2*)&Vbuf[QI][c0 + 8];                  \
    HA = ((w0_.x + w0_.y) + (w1_.x + w1_.y))                               \
       + ((w2_.x + w2_.y) + (w3_.x + w3_.y)) + w4_.x;                      \
    HB = HA + w4_.y - w0_.x;                                               \
} while (0)

#define CC1(AI, AJ, S2, S3, S4) do {                                       \
    const float cross = (S4) - (AI)*(AJ)*inv81;                            \
    const float ivv   = (S2) - (AI)*(AI)*inv81;                            \
    const float jvv   = (S3) - (AJ)*(AJ)*inv81;                            \
    acc += cross * cross * __builtin_amdgcn_rcpf(ivv * jvv + 1e-5f);       \
} while (0)

// exchange V through LDS, horizontal 9-sums, accumulate cc for 2 cols
#define EMIT() do {                                                        \
    *(float2*)&Vbuf[0][4 + c0] = make_float2(VI0, VI1);                    \
    *(float2*)&Vbuf[1][4 + c0] = make_float2(VJ0, VJ1);                    \
    *(float2*)&Vbuf[2][4 + c0] = make_float2(VA0, VA1);                    \
    *(float2*)&Vbuf[3][4 + c0] = make_float2(VB0, VB1);                    \
    *(float2*)&Vbuf[4][4 + c0] = make_float2(VC0, VC1);                    \
    __syncthreads();                                                       \
    float HI0, HI1, HJ0, HJ1, HA0, HA1, HB0, HB1, HC0, HC1;                \
    HWIN(0, HI0, HI1);                                                     \
    HWIN(1, HJ0, HJ1);                                                     \
    HWIN(2, HA0, HA1);                                                     \
    HWIN(3, HB0, HB1);                                                     \
    HWIN(4, HC0, HC1);                                                     \
    CC1(HI0, HJ0, HA0, HB0, HC0);                                          \
    CC1(HI1, HJ1, HA1, HB1, HC1);                                          \
    __syncthreads();   /* WAR: next emit's Vbuf writes vs these reads */   \
} while (0)

// one row step: LDS-ring read old / write new (R7's proven pattern),
// V update, emit when K>=8. K is runtime but block-uniform.
#define BODY(K, PI, PJ) do {                                               \
    float4 oldv = make_float4(0.f, 0.f, 0.f, 0.f);                         \
    if ((K) >= 9) oldv = ring[slot][t];                                    \
    ring[slot][t] = make_float4(PI.x, PI.y, PJ.x, PJ.y);                   \
    slot = (slot == 8) ? 0 : slot + 1;                                     \
    VI0 += PI.x - oldv.x;             VI1 += PI.y - oldv.y;                \
    VJ0 += PJ.x - oldv.z;             VJ1 += PJ.y - oldv.w;                \
    VA0 += PI.x*PI.x - oldv.x*oldv.x; VA1 += PI.y*PI.y - oldv.y*oldv.y;    \
    VB0 += PJ.x*PJ.x - oldv.z*oldv.z; VB1 += PJ.y*PJ.y - oldv.w*oldv.w;    \
    VC0 += PI.x*PJ.x - oldv.x*oldv.z; VC1 += PI.y*PJ.y - oldv.y*oldv.w;    \
    if ((K) >= 8) { EMIT(); }                                              \
} while (0)

__global__ __launch_bounds__(256, 4) void ncc_main(const float* __restrict__ I,
                                                   const float* __restrict__ J,
                                                   float* __restrict__ partial) {
    const int t  = threadIdx.x;          // 0..255
    const int s  = blockIdx.x;           // row strip (0..31)
    const int b  = blockIdx.y;           // image
    const int r0 = s * SH;
    const int c0 = 2 * t;                // first owned column (0..510)
    const float inv81 = 1.0f / 81.0f;

    const float* Ib = I + (size_t)b * IMH * IMW;
    const float* Jb = J + (size_t)b * IMH * IMW;

    __shared__ float  Vbuf[5][VROW];     // 10.4 KB exchange buffer
    __shared__ float4 ring[9][256];      // 36.9 KB: 9-row history (I0,I1,J0,J1)

    // zero the 8 pad cols (idx 0..3, 516..519) of each of the 5 Vbuf rows
    if (t < 40) {
        const int q = t >> 3, p = t & 7;
        Vbuf[q][p < 4 ? p : 512 + p] = 0.f;
    }
    __syncthreads();

    float VI0 = 0.f, VI1 = 0.f, VJ0 = 0.f, VJ1 = 0.f;
    float VA0 = 0.f, VA1 = 0.f, VB0 = 0.f, VB1 = 0.f;
    float VC0 = 0.f, VC1 = 0.f;
    float acc = 0.f;
    int slot = 0;

    // 4 named prefetch pairs -- the in-register pipeline (16 floats)
    float2 pa_i, pa_j, pb_i, pb_j, pc_i, pc_j, pd_i, pd_j;
    PREFG(0, pa_i, pa_j);
    PREFG(1, pb_i, pb_j);
    PREFG(2, pc_i, pc_j);
    PREFG(3, pd_i, pd_j);

#pragma unroll 1
    for (int g = 0; g < 6; ++g) {        // 24 rows = 6 groups x 4 steps
        const int K = 4 * g;
        BODY(K,     pa_i, pa_j);  PREFG(K + 4, pa_i, pa_j);
        BODY(K + 1, pb_i, pb_j);  PREFG(K + 5, pb_i, pb_j);
        BODY(K + 2, pc_i, pc_j);  PREFG(K + 6, pc_i, pc_j);
        BODY(K + 3, pd_i, pd_j);  PREFG(K + 7, pd_i, pd_j);
    }

    // block reduction: wave shuffle, then LDS across the 4 waves
    float sum = acc;
#pragma unroll
    for (int off = 32; off > 0; off >>= 1) sum += __shfl_down(sum, off, 64);

    __shared__ float wsum[4];
    if ((t & 63) == 0) wsum[t >> 6] = sum;
    __syncthreads();
    if (t == 0) {
        partial[(size_t)b * NSTRIP + s] = wsum[0] + wsum[1] + wsum[2] + wsum[3];
    }
}

__global__ __launch_bounds__(256) void ncc_reduce(const float* __restrict__ partial,
                                                  float* __restrict__ out) {
    const int t = threadIdx.x;
    double ssum = 0.0;
    for (int idx = t; idx < NPART; idx += 256) ssum += (double)partial[idx];
#pragma unroll
    for (int off = 32; off > 0; off >>= 1) ssum += __shfl_down(ssum, off, 64);

    __shared__ double wsum[4];
    if ((t & 63) == 0) wsum[t >> 6] = ssum;
    __syncthreads();
    if (t == 0) {
        const double total = wsum[0] + wsum[1] + wsum[2] + wsum[3];
        out[0] = (float)(-total / 8388608.0);  // -mean over 32*512*512
    }
}

extern "C" void kernel_launch(void* const* d_in, const int* in_sizes, int n_in,
                              void* d_out, int out_size, void* d_ws, size_t ws_size,
                              hipStream_t stream) {
    const float* I = (const float*)d_in[0];  // y_true
    const float* J = (const float*)d_in[1];  // y_pred
    float* partial = (float*)d_ws;           // NPART floats
    float* out     = (float*)d_out;

    dim3 grid(NSTRIP, BATCH);
    ncc_main<<<grid, 256, 0, stream>>>(I, J, partial);
    ncc_reduce<<<1, 256, 0, stream>>>(partial, out);
}

// Round 20
// 116.600 us; speedup vs baseline: 1.9938x; 1.0061x over previous
//
#include <hip/hip_runtime.h>

// NCC2D fused: 5 box-sums (9x9, zero-pad) + cc + global mean.
// R12 = R8's 1-wave-workgroup halo shape + R11's 4-deep register prefetch
// + SH 16->32. Evidence: R11 (4-deep prefetch on 4-wave blocks) cut main
// 48->40.6us but stayed lockstepped through 32 barriers (VALU 27.7%, occ
// 21.5%); R8 proved 1-wave workgroups make barriers ~free and waves fully
// independent; R10/R11 proved the prefetch pipeline must stay <=~60 live
// floats (LDS ring for history, registers only for the 4-slot pipeline).
// SH=32: halo redundancy 1.25x, and at 12.5KB LDS -> 12 blocks/CU the whole
// 2048-block grid is ONE co-resident generation (no tail).
// Per 64-thread block (wave == workgroup), 128col x 32row output tile:
//   * 2 core cols/lane (float2) + 1 halo col on lanes 0..7 (R8-verified).
//   * 9-row raw-row history in LDS ring (ring read/write same lane-addr,
//     program order, no fence needed).
//   * 4 named prefetch slots, issue-to-consume gap 3 steps ~ HBM latency.
//   * EMIT via per-block Vbuf: wave-level __syncthreads (near-free).
// d_ws: 2048 block partials (float). Kernel 2 reduces in double -> -mean.

#define BATCH     32
#define IMH       512
#define IMW       512
#define SH        32          // output rows per block
#define NROWSTRIP 16          // 512/32
#define NCOLSTRIP 4           // 512/128
#define CBW       128         // output cols per block
#define NK        (SH + 8)    // input rows per block (40 = 10*4)
#define VROW      136         // 4 halo + 128 + 4 halo
#define NPART     (BATCH * NROWSTRIP * NCOLSTRIP)   // 2048

// guarded prefetch of input row KK: 2 core cols + halo col (lanes 0..7)
#define PREFG(KK, CI, CJ, HI, HJ) do {                                     \
    const int kk_ = (KK);                                                  \
    const int ri_ = r0 - 4 + kk_;                                          \
    CI = make_float2(0.f, 0.f); CJ = make_float2(0.f, 0.f);                \
    HI = 0.f; HJ = 0.f;                                                    \
    if (kk_ < NK && (unsigned)ri_ < (unsigned)IMH) {                       \
        const float* rI_ = Ib + (size_t)ri_ * IMW;                         \
        const float* rJ_ = Jb + (size_t)ri_ * IMW;                         \
        CI = *(const float2*)(rI_ + cc0);                                  \
        CJ = *(const float2*)(rJ_ + cc0);                                  \
        if (u < 8 && (unsigned)hc < (unsigned)IMW) {                       \
            HI = rI_[hc]; HJ = rJ_[hc];                                    \
        }                                                                  \
    }                                                                      \
} while (0)

// horizontal 9-window sums for the 2 owned cols from Vbuf row QI
#define HWIN(QI, HA, HB) do {                                              \
    const float2 w0_ = *(const float2*)&Vbuf[QI][l0];                      \
    const float2 w1_ = *(const float2*)&Vbuf[QI][l0 + 2];                  \
    const float2 w2_ = *(const float2*)&Vbuf[QI][l0 + 4];                  \
    const float2 w3_ = *(const float2*)&Vbuf[QI][l0 + 6];                  \
    const float2 w4_ = *(const float2*)&Vbuf[QI][l0 + 8];                  \
    HA = ((w0_.x + w0_.y) + (w1_.x + w1_.y))                               \
       + ((w2_.x + w2_.y) + (w3_.x + w3_.y)) + w4_.x;                      \
    HB = HA + w4_.y - w0_.x;                                               \
} while (0)

#define CC1(AI, AJ, S2, S3, S4) do {                                       \
    const float cross = (S4) - (AI)*(AJ)*inv81;                            \
    const float ivv   = (S2) - (AI)*(AI)*inv81;                            \
    const float jvv   = (S3) - (AJ)*(AJ)*inv81;                            \
    acc += cross * cross * __builtin_amdgcn_rcpf(ivv * jvv + 1e-5f);       \
} while (0)

// exchange V through Vbuf, horizontal 9-sums, accumulate cc (2 cols)
#define EMIT() do {                                                        \
    *(float2*)&Vbuf[0][4 + l0] = make_float2(VI0, VI1);                    \
    *(float2*)&Vbuf[1][4 + l0] = make_float2(VJ0, VJ1);                    \
    *(float2*)&Vbuf[2][4 + l0] = make_float2(VA0, VA1);                    \
    *(float2*)&Vbuf[3][4 + l0] = make_float2(VB0, VB1);                    \
    *(float2*)&Vbuf[4][4 + l0] = make_float2(VC0, VC1);                    \
    if (u < 8) {                                                           \
        Vbuf[0][hx] = hVI; Vbuf[1][hx] = hVJ; Vbuf[2][hx] = hVA;           \
        Vbuf[3][hx] = hVB; Vbuf[4][hx] = hVC;                              \
    }                                                                      \
    __syncthreads();   /* 1-wave workgroup: near-free fence */             \
    float HI0, HI1, HJ0, HJ1, HA0, HA1, HB0, HB1, HC0, HC1;                \
    HWIN(0, HI0, HI1);                                                     \
    HWIN(1, HJ0, HJ1);                                                     \
    HWIN(2, HA0, HA1);                                                     \
    HWIN(3, HB0, HB1);                                                     \
    HWIN(4, HC0, HC1);                                                     \
    CC1(HI0, HJ0, HA0, HB0, HC0);                                          \
    CC1(HI1, HJ1, HA1, HB1, HC1);                                          \
    __syncthreads();   /* WAR fence before next EMIT's writes */           \
} while (0)

// one row step: LDS-ring old/new (same lane addr -> program order),
// V update (core 2 cols + halo col), emit when K>=8.
#define BODY(K, CI, CJ, HI, HJ) do {                                       \
    float4 oldv = make_float4(0.f, 0.f, 0.f, 0.f);                         \
    float2 oldh = make_float2(0.f, 0.f);                                   \
    if ((K) >= 9) {                                                        \
        oldv = ring[slot][u];                                              \
        if (u < 8) oldh = ringH[slot][u];                                  \
    }                                                                      \
    ring[slot][u] = make_float4(CI.x, CI.y, CJ.x, CJ.y);                   \
    if (u < 8) ringH[slot][u] = make_float2(HI, HJ);                       \
    slot = (slot == 8) ? 0 : slot + 1;                                     \
    VI0 += CI.x - oldv.x;             VI1 += CI.y - oldv.y;                \
    VJ0 += CJ.x - oldv.z;             VJ1 += CJ.y - oldv.w;                \
    VA0 += CI.x*CI.x - oldv.x*oldv.x; VA1 += CI.y*CI.y - oldv.y*oldv.y;    \
    VB0 += CJ.x*CJ.x - oldv.z*oldv.z; VB1 += CJ.y*CJ.y - oldv.w*oldv.w;    \
    VC0 += CI.x*CJ.x - oldv.x*oldv.z; VC1 += CI.y*CJ.y - oldv.y*oldv.w;    \
    hVI += HI - oldh.x;               hVJ += HJ - oldh.y;                  \
    hVA += HI*HI - oldh.x*oldh.x;                                          \
    hVB += HJ*HJ - oldh.y*oldh.y;                                          \
    hVC += HI*HJ - oldh.x*oldh.y;                                          \
    if ((K) >= 8) { EMIT(); }                                              \
} while (0)

__global__ __launch_bounds__(64) void ncc_main(const float* __restrict__ I,
                                               const float* __restrict__ J,
                                               float* __restrict__ partial) {
    const int u    = threadIdx.x;        // 0..63
    const int cs   = blockIdx.x;         // col strip (0..3)
    const int s    = blockIdx.y;         // row strip (0..15)
    const int b    = blockIdx.z;         // image
    const int r0   = s * SH;
    const int cblk = cs * CBW;
    const int cc0  = cblk + 2 * u;       // first owned core col (abs)
    // halo col for lanes 0..7: 0-3 -> cblk-4..cblk-1, 4-7 -> cblk+128..131
    const int hc   = cblk + (u < 4 ? u - 4 : 124 + u);
    const int hx   = (u < 4) ? u : 128 + u;   // Vbuf idx of halo col
    const int l0   = 2 * u;              // HWIN base idx (col cc0-4)
    const float inv81 = 1.0f / 81.0f;

    const float* Ib = I + (size_t)b * IMH * IMW;
    const float* Jb = J + (size_t)b * IMH * IMW;

    __shared__ float4 ring[9][64];       // 9.2 KB core history (I0,I1,J0,J1)
    __shared__ float2 ringH[9][8];       // 576 B halo history (I,J)
    __shared__ float  Vbuf[5][VROW];     // 2.7 KB exchange buffer

    float VI0 = 0.f, VI1 = 0.f, VJ0 = 0.f, VJ1 = 0.f;
    float VA0 = 0.f, VA1 = 0.f, VB0 = 0.f, VB1 = 0.f;
    float VC0 = 0.f, VC1 = 0.f;
    float hVI = 0.f, hVJ = 0.f, hVA = 0.f, hVB = 0.f, hVC = 0.f;
    float acc = 0.f;
    int slot = 0;

    // 4 named prefetch slots (24 floats) -- the in-register pipeline
    float2 pa_i, pa_j, pb_i, pb_j, pc_i, pc_j, pd_i, pd_j;
    float  pa_hi, pa_hj, pb_hi, pb_hj, pc_hi, pc_hj, pd_hi, pd_hj;
    PREFG(0, pa_i, pa_j, pa_hi, pa_hj);
    PREFG(1, pb_i, pb_j, pb_hi, pb_hj);
    PREFG(2, pc_i, pc_j, pc_hi, pc_hj);
    PREFG(3, pd_i, pd_j, pd_hi, pd_hj);

#pragma unroll 1
    for (int g = 0; g < NK / 4; ++g) {   // 40 rows = 10 groups x 4 steps
        const int K = 4 * g;
        BODY(K,     pa_i, pa_j, pa_hi, pa_hj);
        PREFG(K + 4, pa_i, pa_j, pa_hi, pa_hj);
        BODY(K + 1, pb_i, pb_j, pb_hi, pb_hj);
        PREFG(K + 5, pb_i, pb_j, pb_hi, pb_hj);
        BODY(K + 2, pc_i, pc_j, pc_hi, pc_hj);
        PREFG(K + 6, pc_i, pc_j, pc_hi, pc_hj);
        BODY(K + 3, pd_i, pd_j, pd_hi, pd_hj);
        PREFG(K + 7, pd_i, pd_j, pd_hi, pd_hj);
    }

    // single-wave reduction; lane 0 writes the block partial
    float sum = acc;
#pragma unroll
    for (int off = 32; off > 0; off >>= 1) sum += __shfl_down(sum, off, 64);
    if (u == 0) {
        partial[((size_t)b * NROWSTRIP + s) * NCOLSTRIP + cs] = sum;
    }
}

__global__ __launch_bounds__(256) void ncc_reduce(const float* __restrict__ partial,
                                                  float* __restrict__ out) {
    const int t = threadIdx.x;
    double ssum = 0.0;
    for (int idx = t; idx < NPART; idx += 256) ssum += (double)partial[idx];
#pragma unroll
    for (int off = 32; off > 0; off >>= 1) ssum += __shfl_down(ssum, off, 64);

    __shared__ double wsum[4];
    if ((t & 63) == 0) wsum[t >> 6] = ssum;
    __syncthreads();
    if (t == 0) {
        const double total = wsum[0] + wsum[1] + wsum[2] + wsum[3];
        out[0] = (float)(-total / 8388608.0);  // -mean over 32*512*512
    }
}

extern "C" void kernel_launch(void* const* d_in, const int* in_sizes, int n_in,
                              void* d_out, int out_size, void* d_ws, size_t ws_size,
                              hipStream_t stream) {
    const float* I = (const float*)d_in[0];  // y_true
    const float* J = (const float*)d_in[1];  // y_pred
    float* partial = (float*)d_ws;           // NPART floats
    float* out     = (float*)d_out;

    dim3 grid(NCOLSTRIP, NROWSTRIP, BATCH);
    ncc_main<<<grid, 64, 0, stream>>>(I, J, partial);
    ncc_reduce<<<1, 256, 0, stream>>>(partial, out);
}